// Round 15
// baseline (137.611 us; speedup 1.0000x reference)
//
#include <hip/hip_runtime.h>
#include <stdint.h>

#define NB 64
#define NN 1024
#define CDIM 512
#define KK 64

typedef __attribute__((ext_vector_type(4))) float f32x4;
typedef __attribute__((ext_vector_type(8))) short short8;
typedef __attribute__((ext_vector_type(4))) unsigned short u16x4;

__device__ __forceinline__ unsigned short f2bf(float f) {
  unsigned int u = __float_as_uint(f);
  return (unsigned short)((u + 0x7fffu + ((u >> 16) & 1u)) >> 16);
}

// ---------------- K0: centers fp32 -> bf16 ----------------
__global__ __launch_bounds__(256) void k0_cvt(const float* __restrict__ cc,
                                              unsigned short* __restrict__ ccb) {
  int i = blockIdx.x * 256 + threadIdx.x;   // grid sized exactly KK*CDIM/256
  ccb[i] = f2bf(cc[i]);
}

// ---- K_FUSED v2: logits + softmax + agg, single x pass; 512 thr = 8 waves ----
// grid (4 n-quarters, 64 b) = 256 blocks = 1/CU, 8 waves/CU (2/SIMD).
// Block owns 256 n = 4 chunks of 64. Roles per wave w:
//   stage:  rows [w*8, w*8+8) of chunk (linear 1KB loads; T14 prefetch)
//   MFMA1:  rt=w>>1 rows [rt*16,+16), kh=w&1 k-tiles {2kh,2kh+1}; kh0 packs xT
//   softmax: kh0 waves only, after pacc exchange (static indices)
//   MFMA2:  kt=w>>1 k-tile, chh=w&1 c-half; acc2[16] (64 VGPR)
// LDS strides: xT_sm/a_sm 36 u32 (16B-aligned rows); xT word idx XOR'd with
// ((c>>3)&3)<<3 to spread lg-collisions. fbuf (aliases x_sm) stride 260 f32.
__global__ __launch_bounds__(512, 2) void k_fused(const float* __restrict__ x,
    const unsigned short* __restrict__ ccb, float* __restrict__ a_sum,
    float* __restrict__ pagg) {
  const int q = blockIdx.x;
  const int b = blockIdx.y;
  const int tid = threadIdx.x;
  const int w = tid >> 6;
  const int l = tid & 63;
  const int lr = l & 15;
  const int lg = l >> 4;
  const int codd = l & 1;
  const int rt = w >> 1;   // MFMA1 row-tile / MFMA2 k-tile (kt)
  const int kh = w & 1;    // MFMA1 k-half  / MFMA2 c-half (chh)

  __shared__ unsigned short x_sm[64 * 520];   // 66,560 B (fbuf alias, stride 260 f32)
  __shared__ unsigned int xT_sm[512 * 36];    // 73,728 B
  __shared__ unsigned int a_sm[64 * 36];      //  9,216 B
  __shared__ f32x4 pacc[4][2][64];            //  8,192 B

  f32x4 acc2[16];
  #pragma unroll
  for (int i = 0; i < 16; ++i) acc2[i] = (f32x4){0.f, 0.f, 0.f, 0.f};
  float asr0 = 0.f, asr1 = 0.f, asr2 = 0.f, asr3 = 0.f;

  const int nrow = (rt << 4) + lr;            // MFMA1 A-row (chunk-local)
  const int xsw = (nrow & 7) << 4;
  const unsigned short* cb0 = ccb + (((kh << 1) << 4) + lr) * CDIM + (lg << 3);
  const unsigned short* cb1 = cb0 + 16 * CDIM;
  const float* xbase = x + ((size_t)b * NN + (q << 8) + (w << 3)) * CDIM;

  // ---- prologue: stage chunk 0 ----
  {
    #pragma unroll
    for (int rr = 0; rr < 8; ++rr) {
      const float* rp = xbase + (size_t)rr * CDIM;
      f32x4 va = *(const f32x4*)(rp + (l << 2));
      f32x4 vb = *(const f32x4*)(rp + 256 + (l << 2));
      const int n = (w << 3) + rr;
      const int sw = (n & 7) << 4;
      u16x4 pa, pb;
      pa[0] = f2bf(va[0]); pa[1] = f2bf(va[1]);
      pa[2] = f2bf(va[2]); pa[3] = f2bf(va[3]);
      pb[0] = f2bf(vb[0]); pb[1] = f2bf(vb[1]);
      pb[2] = f2bf(vb[2]); pb[3] = f2bf(vb[3]);
      *(u16x4*)&x_sm[(n << 9) + (((l << 2)) ^ sw)] = pa;
      *(u16x4*)&x_sm[(n << 9) + (((l << 2) + 256) ^ sw)] = pb;
    }
  }
  __syncthreads();

  for (int ch = 0; ch < 4; ++ch) {
    // ---- T14: issue next chunk's loads ----
    f32x4 xr[16];
    if (ch < 3) {
      const float* xn = xbase + (size_t)((ch + 1) << 6) * CDIM;
      #pragma unroll
      for (int rr = 0; rr < 8; ++rr) {
        xr[2 * rr]     = *(const f32x4*)(xn + (size_t)rr * CDIM + (l << 2));
        xr[2 * rr + 1] = *(const f32x4*)(xn + (size_t)rr * CDIM + 256 + (l << 2));
      }
    }

    // ---- MFMA1 (+ xT pack by kh0) ----
    f32x4 acc1a = {0.f, 0.f, 0.f, 0.f}, acc1b = acc1a;
    #pragma unroll
    for (int s = 0; s < 16; ++s) {
      const int cs = s << 5;
      short8 af = *(const short8*)&x_sm[(nrow << 9) + ((cs + (lg << 3)) ^ xsw)];
      short8 bq0 = *(const short8*)(cb0 + cs);
      short8 bq1 = *(const short8*)(cb1 + cs);
      acc1a = __builtin_amdgcn_mfma_f32_16x16x32_bf16(af, bq0, acc1a, 0, 0, 0);
      acc1b = __builtin_amdgcn_mfma_f32_16x16x32_bf16(af, bq1, acc1b, 0, 0, 0);
      if (kh == 0) {
        #pragma unroll
        for (int qq = 0; qq < 4; ++qq) {
          unsigned int own = ((const unsigned int*)&af)[qq];
          unsigned int oth = (unsigned int)__shfl_xor((int)own, 1);
          unsigned int v = codd ? ((oth >> 16) | (own & 0xffff0000u))
                                : ((own & 0xffffu) | (oth << 16));
          const int c = cs + (lg << 3) + (qq << 1) + codd;
          const int np = (rt << 3) + (lr >> 1);
          xT_sm[c * 36 + (np ^ (((c >> 3) & 3) << 3))] = v;
        }
      }
    }
    if (kh == 1) {
      pacc[rt][0][l] = acc1a;
      pacc[rt][1][l] = acc1b;
    }
    __syncthreads();

    // ---- softmax (kh0 only) + a_sm pack + asum ----
    if (kh == 0) {
      f32x4 t0 = acc1a, t1 = acc1b;
      f32x4 t2 = pacc[rt][0][l];
      f32x4 t3 = pacc[rt][1][l];
      #pragma unroll
      for (int j = 0; j < 4; ++j) {
        float m = fmaxf(fmaxf(t0[j], t1[j]), fmaxf(t2[j], t3[j]));
        m = fmaxf(m, __shfl_xor(m, 1));
        m = fmaxf(m, __shfl_xor(m, 2));
        m = fmaxf(m, __shfl_xor(m, 4));
        m = fmaxf(m, __shfl_xor(m, 8));
        float e0 = __expf(t0[j] - m);
        float e1 = __expf(t1[j] - m);
        float e2 = __expf(t2[j] - m);
        float e3 = __expf(t3[j] - m);
        float s = e0 + e1 + e2 + e3;
        s += __shfl_xor(s, 1); s += __shfl_xor(s, 2);
        s += __shfl_xor(s, 4); s += __shfl_xor(s, 8);
        float inv = 1.0f / s;
        t0[j] = e0 * inv; t1[j] = e1 * inv;
        t2[j] = e2 * inv; t3[j] = e3 * inv;
        asr0 += t0[j]; asr1 += t1[j]; asr2 += t2[j]; asr3 += t3[j];
      }
      #pragma unroll
      for (int jp = 0; jp < 2; ++jp) {
        const int colb = (rt << 3) + (lg << 1) + jp;
        a_sm[( lr       ) * 36 + colb] =
            (unsigned int)f2bf(t0[2 * jp]) | ((unsigned int)f2bf(t0[2 * jp + 1]) << 16);
        a_sm[(16 + lr) * 36 + colb] =
            (unsigned int)f2bf(t1[2 * jp]) | ((unsigned int)f2bf(t1[2 * jp + 1]) << 16);
        a_sm[(32 + lr) * 36 + colb] =
            (unsigned int)f2bf(t2[2 * jp]) | ((unsigned int)f2bf(t2[2 * jp + 1]) << 16);
        a_sm[(48 + lr) * 36 + colb] =
            (unsigned int)f2bf(t3[2 * jp]) | ((unsigned int)f2bf(t3[2 * jp + 1]) << 16);
      }
    }
    __syncthreads();

    // ---- MFMA2: k-tile rt(kt), c-half kh(chh) ----
    {
      const unsigned int* asmp = a_sm + ((rt << 4) + lr) * 36;
      #pragma unroll
      for (int ns = 0; ns < 2; ++ns) {
        short8 af2 = *(const short8*)(asmp + (ns << 4) + (lg << 2));
        #pragma unroll
        for (int ct = 0; ct < 16; ++ct) {
          const int c = (kh << 8) + (ct << 4) + lr;
          const int wofs = (((ns << 4) + (lg << 2)) ^ (((c >> 3) & 3) << 3));
          short8 bf2 = *(const short8*)&xT_sm[c * 36 + wofs];
          acc2[ct] = __builtin_amdgcn_mfma_f32_16x16x32_bf16(af2, bf2, acc2[ct], 0, 0, 0);
        }
      }
    }
    // ---- write prefetched x into x_sm ----
    if (ch < 3) {
      #pragma unroll
      for (int rr = 0; rr < 8; ++rr) {
        const int n = (w << 3) + rr;
        const int sw = (n & 7) << 4;
        f32x4 va = xr[2 * rr];
        f32x4 vb = xr[2 * rr + 1];
        u16x4 pa, pb;
        pa[0] = f2bf(va[0]); pa[1] = f2bf(va[1]);
        pa[2] = f2bf(va[2]); pa[3] = f2bf(va[3]);
        pb[0] = f2bf(vb[0]); pb[1] = f2bf(vb[1]);
        pb[2] = f2bf(vb[2]); pb[3] = f2bf(vb[3]);
        *(u16x4*)&x_sm[(n << 9) + (((l << 2)) ^ sw)] = pa;
        *(u16x4*)&x_sm[(n << 9) + (((l << 2) + 256) ^ sw)] = pb;
      }
    }
    __syncthreads();
  }

  // ---- a_sum atomics (kh0 waves; reduce over lg first) ----
  if (kh == 0) {
    float s0 = asr0, s1 = asr1, s2 = asr2, s3 = asr3;
    s0 += __shfl_xor(s0, 16); s0 += __shfl_xor(s0, 32);
    s1 += __shfl_xor(s1, 16); s1 += __shfl_xor(s1, 32);
    s2 += __shfl_xor(s2, 16); s2 += __shfl_xor(s2, 32);
    s3 += __shfl_xor(s3, 16); s3 += __shfl_xor(s3, 32);
    if (lg == 0) {
      atomicAdd(&a_sum[(b << 6) + lr], s0);
      atomicAdd(&a_sum[(b << 6) + 16 + lr], s1);
      atomicAdd(&a_sum[(b << 6) + 32 + lr], s2);
      atomicAdd(&a_sum[(b << 6) + 48 + lr], s3);
    }
  }

  // ---- partial agg -> fbuf -> linear stores (2 c-half passes) ----
  float* fbuf = (float*)x_sm;   // stride 260 f32
  float* pg = pagg + (((size_t)((b << 2) + q)) << 15);
  #pragma unroll
  for (int pass = 0; pass < 2; ++pass) {
    __syncthreads();
    if (kh == pass) {
      #pragma unroll
      for (int ct = 0; ct < 16; ++ct) {
        #pragma unroll
        for (int j = 0; j < 4; ++j) {
          fbuf[((rt << 4) + (lg << 2) + j) * 260 + (ct << 4) + lr] = acc2[ct][j];
        }
      }
    }
    __syncthreads();
    #pragma unroll
    for (int i = 0; i < 8; ++i) {
      const int f = (i << 9) + tid;        // 0..4095 f32x4 ids
      const int k = f >> 6;
      const int c4 = (f & 63) << 2;
      f32x4 v = *(const f32x4*)&fbuf[k * 260 + c4];
      *(f32x4*)(pg + (k << 9) + (pass << 8) + c4) = v;
    }
  }
}

// ---- K_FINAL: vlad = sum_q pagg - a_sum*cc; out write; sumsq atomics ----
__global__ __launch_bounds__(256) void k_final(const float* __restrict__ pagg,
    const float* __restrict__ a_sum, const float* __restrict__ cc,
    float* __restrict__ out, float* __restrict__ sumsq) {
  const int b = blockIdx.y;
  const int sl = blockIdx.x;
  const int tid = threadIdx.x;
  __shared__ float red[4];
  const float* p0 = pagg + (((size_t)(b << 2)) << 15) + (sl << 11);
  float lsum = 0.f;
  #pragma unroll
  for (int i = 0; i < 2; ++i) {
    const int f = (i << 10) + (tid << 2);
    f32x4 v0 = *(const f32x4*)(p0 + f);
    f32x4 v1 = *(const f32x4*)(p0 + (1 << 15) + f);
    f32x4 v2 = *(const f32x4*)(p0 + (2 << 15) + f);
    f32x4 v3 = *(const f32x4*)(p0 + (3 << 15) + f);
    const int k = ((sl << 11) + f) >> 9;
    const float as = a_sum[(b << 6) + k];
    f32x4 cv = *(const f32x4*)(cc + (sl << 11) + f);
    f32x4 r;
    r[0] = v0[0] + v1[0] + v2[0] + v3[0] - as * cv[0];
    r[1] = v0[1] + v1[1] + v2[1] + v3[1] - as * cv[1];
    r[2] = v0[2] + v1[2] + v2[2] + v3[2] - as * cv[2];
    r[3] = v0[3] + v1[3] + v2[3] + v3[3] - as * cv[3];
    *(f32x4*)(out + ((size_t)b << 15) + (sl << 11) + f) = r;
    lsum += r[0] * r[0] + r[1] * r[1] + r[2] * r[2] + r[3] * r[3];
  }
  lsum += __shfl_xor(lsum, 1);  lsum += __shfl_xor(lsum, 2);
  lsum += __shfl_xor(lsum, 4);  lsum += __shfl_xor(lsum, 8);
  lsum += __shfl_xor(lsum, 16); lsum += __shfl_xor(lsum, 32);
  if ((tid & 63) == 0) red[tid >> 6] = lsum;
  __syncthreads();
  if (tid == 0) atomicAdd(&sumsq[b], red[0] + red[1] + red[2] + red[3]);
}

// ---------------- K3: l2 normalize per batch ----------------
__global__ __launch_bounds__(256) void k3_norm(float* __restrict__ out,
                                               const float* __restrict__ sumsq) {
  int idx = blockIdx.x * 256 + threadIdx.x;   // grid exact: 2048*256 = 2M/4
  int b = idx >> 13;                          // 8192 float4 per batch
  float s = sumsq[b];
  float scale = 1.0f / sqrtf(fmaxf(s, 1e-12f));
  f32x4* io = (f32x4*)out;
  f32x4 v = io[idx];
  v[0] *= scale; v[1] *= scale; v[2] *= scale; v[3] *= scale;
  io[idx] = v;
}

extern "C" void kernel_launch(void* const* d_in, const int* in_sizes, int n_in,
                              void* d_out, int out_size, void* d_ws, size_t ws_size,
                              hipStream_t stream) {
  const float* x  = (const float*)d_in[0];
  const float* cc = (const float*)d_in[1];
  float* out = (float*)d_out;
  char* ws = (char*)d_ws;
  // ws: [ccb 64KiB @0][a_sum 16KiB @64K][sumsq 256B @80K][pagg 32MiB @1MiB]
  unsigned short* ccb = (unsigned short*)ws;
  float* a_sum = (float*)(ws + (64u << 10));
  float* sumsq = (float*)(ws + (80u << 10));
  float* pagg  = (float*)(ws + (1u << 20));

  (void)hipMemsetAsync(a_sum, 0, NB * KK * 4 + NB * 4, stream);
  k0_cvt<<<dim3((KK * CDIM) / 256), 256, 0, stream>>>(cc, ccb);
  k_fused<<<dim3(4, NB), 512, 0, stream>>>(x, ccb, a_sum, pagg);
  k_final<<<dim3(16, NB), 256, 0, stream>>>(pagg, a_sum, cc, out, sumsq);
  k3_norm<<<dim3(2048), 256, 0, stream>>>(out, sumsq);
}

// Round 16
// 74.124 us; speedup vs baseline: 1.8565x; 1.8565x over previous
//
#include <hip/hip_runtime.h>
#include <stdint.h>

#define NB 64
#define NN 1024
#define CDIM 512
#define KK 64

typedef __attribute__((ext_vector_type(4))) float f32x4;
typedef __attribute__((ext_vector_type(8))) short short8;

__device__ __forceinline__ unsigned short f2bf(float f) {
  unsigned int u = __float_as_uint(f);
  return (unsigned short)((u + 0x7fffu + ((u >> 16) & 1u)) >> 16);
}
__device__ __forceinline__ float bf2f(unsigned short h) {
  return __uint_as_float(((unsigned int)h) << 16);
}

__device__ __forceinline__ void lgkm_barrier() {
  // raw workgroup barrier that does NOT drain vmcnt (k2 only)
  asm volatile("s_waitcnt lgkmcnt(0)" ::: "memory");
  __builtin_amdgcn_sched_barrier(0);
  __builtin_amdgcn_s_barrier();
}

// ---------------- K0: centers fp32 -> bf16 ----------------
__global__ __launch_bounds__(256) void k0_cvt(const float* __restrict__ cc,
                                              unsigned short* __restrict__ ccb) {
  int i = blockIdx.x * 256 + threadIdx.x;   // grid sized exactly KK*CDIM/256
  ccb[i] = f2bf(cc[i]);
}

// ---- K1: logits + softmax + a^T + xT — c-split wave pairs, STATIC reg indexing ----
// grid: (8, 64 b) = 512 blocks, 256 thr = 4 waves = 2 pairs x 2 c-halves
// -> 2 blocks/CU = 8 waves/CU (2/SIMD) for latency hiding.
// Pair p = w>>1 owns n-chunk nc = bx*2+p; wave ch = w&1 owns c-half ch*256..+256.
// ALL acc[] indices are compile-time literals (rule #20): duty split is a
// wave-uniform if(ch==0)/else with macro-expanded bodies.
#define SM_AND_PACK(TN)                                                        \
  do {                                                                         \
    _Pragma("unroll")                                                          \
    for (int j = 0; j < 4; ++j) {                                              \
      float m = fmaxf(fmaxf(acc[TN][0][j], acc[TN][1][j]),                     \
                      fmaxf(acc[TN][2][j], acc[TN][3][j]));                    \
      m = fmaxf(m, __shfl_xor(m, 1));                                          \
      m = fmaxf(m, __shfl_xor(m, 2));                                          \
      m = fmaxf(m, __shfl_xor(m, 4));                                          \
      m = fmaxf(m, __shfl_xor(m, 8));                                          \
      float e0 = __expf(acc[TN][0][j] - m);                                    \
      float e1 = __expf(acc[TN][1][j] - m);                                    \
      float e2 = __expf(acc[TN][2][j] - m);                                    \
      float e3 = __expf(acc[TN][3][j] - m);                                    \
      float s = e0 + e1 + e2 + e3;                                             \
      s += __shfl_xor(s, 1); s += __shfl_xor(s, 2);                            \
      s += __shfl_xor(s, 4); s += __shfl_xor(s, 8);                            \
      float inv = 1.0f / s;                                                    \
      acc[TN][0][j] = e0 * inv;                                                \
      acc[TN][1][j] = e1 * inv;                                                \
      acc[TN][2][j] = e2 * inv;                                                \
      acc[TN][3][j] = e3 * inv;                                                \
    }                                                                          \
    _Pragma("unroll")                                                          \
    for (int tk = 0; tk < 4; ++tk) {                                           \
      _Pragma("unroll")                                                        \
      for (int jp = 0; jp < 2; ++jp) {                                         \
        unsigned int v = (unsigned int)f2bf(acc[TN][tk][2 * jp]) |             \
                         ((unsigned int)f2bf(acc[TN][tk][2 * jp + 1]) << 16);  \
        asw[((tk << 4) + lr) * 33 + ((TN) << 3) + (lg << 1) + jp] = v;         \
      }                                                                        \
    }                                                                          \
  } while (0)

__global__ __launch_bounds__(256, 2) void k1_assign(const float* __restrict__ x,
    const unsigned short* __restrict__ ccb, unsigned int* __restrict__ a_t32,
    unsigned int* __restrict__ xT32) {
  const int b = blockIdx.y;
  const int tid = threadIdx.x;
  const int w = tid >> 6;
  const int l = tid & 63;
  const int lr = l & 15;
  const int lg = l >> 4;
  const int pair = w >> 1;
  const int ch = w & 1;
  const int nc = (blockIdx.x << 1) + pair;
  const int n0 = nc << 6;
  const int cbase = ch << 8;
  const int codd = l & 1;

  __shared__ unsigned int xsw_all[4][32 * 33];   // per-wave transpose slabs
  __shared__ unsigned int asw_all[2][64 * 33];   // per-pair a slabs
  __shared__ f32x4 pacc[2][2][2][4][64];         // [pair][writer_ch][t2][tk][lane]

  unsigned int* xsw = xsw_all[w];
  unsigned int* asw = asw_all[pair];

  const float* xr = x + ((size_t)b * NN + n0 + lr) * CDIM + cbase + (lg << 3);
  const unsigned short* cb = ccb + lr * CDIM + cbase + (lg << 3);
  const size_t xTbase = ((size_t)((b << 4) + nc)) << 14;  // *512*32 u32

  f32x4 acc[4][4];
  #pragma unroll
  for (int i = 0; i < 4; ++i)
    #pragma unroll
    for (int j = 0; j < 4; ++j) acc[i][j] = (f32x4){0.f, 0.f, 0.f, 0.f};

  #pragma unroll 2
  for (int step = 0; step < 8; ++step) {
    const int cs = step << 5;           // within the wave's 256-c half
    short8 af[4];
    #pragma unroll
    for (int tn = 0; tn < 4; ++tn) {
      f32x4 xa = *(const f32x4*)(xr + (size_t)(tn << 4) * CDIM + cs);
      f32x4 xb = *(const f32x4*)(xr + (size_t)(tn << 4) * CDIM + cs + 4);
      short8 t;
      t[0] = (short)f2bf(xa[0]); t[1] = (short)f2bf(xa[1]);
      t[2] = (short)f2bf(xa[2]); t[3] = (short)f2bf(xa[3]);
      t[4] = (short)f2bf(xb[0]); t[5] = (short)f2bf(xb[1]);
      t[6] = (short)f2bf(xb[2]); t[7] = (short)f2bf(xb[3]);
      af[tn] = t;
    }
    short8 bq0 = *(const short8*)(cb + cs);
    short8 bq1 = *(const short8*)(cb + 16 * CDIM + cs);
    short8 bq2 = *(const short8*)(cb + 32 * CDIM + cs);
    short8 bq3 = *(const short8*)(cb + 48 * CDIM + cs);
    #pragma unroll
    for (int tn = 0; tn < 4; ++tn) {
      acc[tn][0] = __builtin_amdgcn_mfma_f32_16x16x32_bf16(af[tn], bq0, acc[tn][0], 0, 0, 0);
      acc[tn][1] = __builtin_amdgcn_mfma_f32_16x16x32_bf16(af[tn], bq1, acc[tn][1], 0, 0, 0);
      acc[tn][2] = __builtin_amdgcn_mfma_f32_16x16x32_bf16(af[tn], bq2, acc[tn][2], 0, 0, 0);
      acc[tn][3] = __builtin_amdgcn_mfma_f32_16x16x32_bf16(af[tn], bq3, acc[tn][3], 0, 0, 0);
    }
    // lane-pair transpose af -> private slab (rows = c within step, cols = n-pair)
    #pragma unroll
    for (int tn = 0; tn < 4; ++tn) {
      #pragma unroll
      for (int q = 0; q < 4; ++q) {
        unsigned int own = ((const unsigned int*)&af[tn])[q];
        unsigned int oth = (unsigned int)__shfl_xor((int)own, 1);
        unsigned int v = codd ? ((oth >> 16) | (own & 0xffff0000u))
                              : ((own & 0xffffu) | (oth << 16));
        xsw[((lg << 3) + (q << 1) + codd) * 33 + (tn << 3) + (lr >> 1)] = v;
      }
    }
    // wave-synchronous contiguous drain: 2 c-rows x 128 B per instr
    #pragma unroll
    for (int i = 0; i < 16; ++i) {
      const int row = (i << 1) + (l >> 5);
      xT32[xTbase + ((size_t)(cbase + cs + row) << 5) + (l & 31)] =
          xsw[row * 33 + (l & 31)];
    }
  }

  // ---- exchange partial logits (STATIC indices, wave-uniform branch) ----
  if (ch == 0) {
    #pragma unroll
    for (int tk = 0; tk < 4; ++tk) {
      pacc[pair][0][0][tk][l] = acc[2][tk];
      pacc[pair][0][1][tk][l] = acc[3][tk];
    }
  } else {
    #pragma unroll
    for (int tk = 0; tk < 4; ++tk) {
      pacc[pair][1][0][tk][l] = acc[0][tk];
      pacc[pair][1][1][tk][l] = acc[1][tk];
    }
  }
  __syncthreads();
  if (ch == 0) {
    #pragma unroll
    for (int tk = 0; tk < 4; ++tk) {
      f32x4 o0 = pacc[pair][1][0][tk][l];
      f32x4 o1 = pacc[pair][1][1][tk][l];
      acc[0][tk][0] += o0[0]; acc[0][tk][1] += o0[1];
      acc[0][tk][2] += o0[2]; acc[0][tk][3] += o0[3];
      acc[1][tk][0] += o1[0]; acc[1][tk][1] += o1[1];
      acc[1][tk][2] += o1[2]; acc[1][tk][3] += o1[3];
    }
    SM_AND_PACK(0);
    SM_AND_PACK(1);
  } else {
    #pragma unroll
    for (int tk = 0; tk < 4; ++tk) {
      f32x4 o0 = pacc[pair][0][0][tk][l];
      f32x4 o1 = pacc[pair][0][1][tk][l];
      acc[2][tk][0] += o0[0]; acc[2][tk][1] += o0[1];
      acc[2][tk][2] += o0[2]; acc[2][tk][3] += o0[3];
      acc[3][tk][0] += o1[0]; acc[3][tk][1] += o1[1];
      acc[3][tk][2] += o1[2]; acc[3][tk][3] += o1[3];
    }
    SM_AND_PACK(2);
    SM_AND_PACK(3);
  }
  __syncthreads();

  // ---- cooperative a_t drain: both pairs, 16 u32/thread, coalesced ----
  {
    const size_t atb0 = ((size_t)((b << 4) + (blockIdx.x << 1))) << 11;
    #pragma unroll
    for (int i = 0; i < 16; ++i) {
      const int f = (i << 8) + tid;       // 0..4095
      const int p = f >> 11;              // pair
      const int k = (f >> 5) & 63;
      const int col = f & 31;
      a_t32[atb0 + (((size_t)p) << 11) + (k << 5) + col] =
          asw_all[p][k * 33 + col];
    }
  }
}

// ---- K2: agg = a^T x via MFMA; chunked inputs; a_sum computed in-kernel ----
// grid: (8 c-slices, 64 b) = 512 blocks, 256 thr = 4 waves (k-split 16 each).
// Per chunk it: stage xT[b][it][c0..c0+64)][64n] (8 KB CONTIGUOUS) via 8 u32
// loads/thread into stride-38 LDS (dbuf); A-frags direct from a_t[b][it][k][n].
// T14 prefetch; raw lgkm-only barriers keep prefetched loads in flight.
#define XRS 38
__global__ __launch_bounds__(256) void k2_agg(
    const unsigned short* __restrict__ a_t, const unsigned int* __restrict__ xT32,
    const float* __restrict__ cc, float* __restrict__ out,
    float* __restrict__ sumsq) {
  const int b = blockIdx.y;
  const int c0 = blockIdx.x << 6;
  const int tid = threadIdx.x;
  const int w = tid >> 6;
  const int l = tid & 63;
  const int lr = l & 15;
  const int lg = l >> 4;

  __shared__ unsigned int xs[2][64 * XRS];  // 9728 B each
  __shared__ float red[4];

  f32x4 acc[4];
  #pragma unroll
  for (int i = 0; i < 4; ++i) acc[i] = (f32x4){0.f, 0.f, 0.f, 0.f};
  float ssum = 0.f;   // per-lane partial of a_sum[k=16w+lr]

  // A-frag pointer: chunk-stride 4096 ush; row k=16w+lr (64 ush), off lg*8
  const unsigned short* ap =
      a_t + (((size_t)(b << 4)) << 12) + (((w << 4) + lr) << 6) + (lg << 3);
  // xT stage pointer: chunk-stride 16384 u32; c-row c0 + tid>>5, col tid&31
  const unsigned int* xg =
      xT32 + (((size_t)(b << 4)) << 14) + ((c0 + (tid >> 5)) << 5) + (tid & 31);

  // ---- prologue: stage chunk 0, load chunk-0 A-frags ----
  #pragma unroll
  for (int p = 0; p < 8; ++p) {
    const int f = (p << 8) + tid;
    xs[0][(f >> 5) * XRS + (f & 31)] = xg[p << 8];
  }
  short8 a_cur0 = *(const short8*)(ap);
  short8 a_cur1 = *(const short8*)(ap + 32);
  lgkm_barrier();

  for (int it = 0; it < 16; ++it) {
    const int cur = it & 1;
    unsigned int xr[8];
    short8 a_nxt0, a_nxt1;
    if (it < 15) {
      const size_t cho = ((size_t)(it + 1)) << 14;      // u32 chunk offset
      const size_t cha = ((size_t)(it + 1)) << 12;      // ush chunk offset
      #pragma unroll
      for (int p = 0; p < 8; ++p) xr[p] = xg[cho + (p << 8)];
      a_nxt0 = *(const short8*)(ap + cha);
      a_nxt1 = *(const short8*)(ap + cha + 32);
    }
    #pragma unroll
    for (int i = 0; i < 8; ++i)
      ssum += bf2f((unsigned short)a_cur0[i]) + bf2f((unsigned short)a_cur1[i]);
    #pragma unroll
    for (int ns = 0; ns < 64; ns += 32) {
      const short8 af = ns == 0 ? a_cur0 : a_cur1;
      #pragma unroll
      for (int ct = 0; ct < 4; ++ct) {
        const int row = (ct << 4) + lr;
        const unsigned long long* bp = (const unsigned long long*)
            &xs[cur][row * XRS + (ns >> 1) + (lg << 2)];
        union { unsigned long long q[2]; short8 s; } u;
        u.q[0] = bp[0];
        u.q[1] = bp[1];
        acc[ct] = __builtin_amdgcn_mfma_f32_16x16x32_bf16(af, u.s, acc[ct], 0, 0, 0);
      }
    }
    if (it < 15) {
      #pragma unroll
      for (int p = 0; p < 8; ++p) {
        const int f = (p << 8) + tid;
        xs[cur ^ 1][(f >> 5) * XRS + (f & 31)] = xr[p];
      }
      a_cur0 = a_nxt0;
      a_cur1 = a_nxt1;
    }
    lgkm_barrier();
  }

  // a_sum reduce over lg groups; lane lr holds a_sum for k=16w+lr
  ssum += __shfl_xor(ssum, 16);
  ssum += __shfl_xor(ssum, 32);

  float lsum = 0.f;
  #pragma unroll
  for (int j = 0; j < 4; ++j) {
    const float asum_e = __shfl(ssum, (lg << 2) + j);   // a_sum[k=16w+lg*4+j]
    #pragma unroll
    for (int ct = 0; ct < 4; ++ct) {
      int k = (w << 4) + (lg << 2) + j;
      int c = c0 + (ct << 4) + lr;
      float v = acc[ct][j] - asum_e * cc[k * CDIM + c];
      out[((size_t)b << 15) + (k << 9) + c] = v;
      lsum += v * v;
    }
  }
  lsum += __shfl_xor(lsum, 1);  lsum += __shfl_xor(lsum, 2);
  lsum += __shfl_xor(lsum, 4);  lsum += __shfl_xor(lsum, 8);
  lsum += __shfl_xor(lsum, 16); lsum += __shfl_xor(lsum, 32);
  if (l == 0) red[w] = lsum;
  __syncthreads();
  if (tid == 0) atomicAdd(&sumsq[b], red[0] + red[1] + red[2] + red[3]);
}

// ---------------- K3: l2 normalize per batch ----------------
__global__ __launch_bounds__(256) void k3_norm(float* __restrict__ out,
                                               const float* __restrict__ sumsq) {
  int idx = blockIdx.x * 256 + threadIdx.x;   // grid exact: 2048*256 = 2M/4
  int b = idx >> 13;                          // 8192 float4 per batch
  float s = sumsq[b];
  float scale = 1.0f / sqrtf(fmaxf(s, 1e-12f));
  f32x4* io = (f32x4*)out;
  f32x4 v = io[idx];
  v[0] *= scale; v[1] *= scale; v[2] *= scale; v[3] *= scale;
  io[idx] = v;
}

extern "C" void kernel_launch(void* const* d_in, const int* in_sizes, int n_in,
                              void* d_out, int out_size, void* d_ws, size_t ws_size,
                              hipStream_t stream) {
  const float* x  = (const float*)d_in[0];
  const float* cc = (const float*)d_in[1];
  float* out = (float*)d_out;
  char* ws = (char*)d_ws;
  // ws: [a_t bf16 8MiB][ccb 64KiB][sumsq 256B] ... [xT 64MiB @16MiB]
  unsigned short* a_t = (unsigned short*)ws;
  unsigned int* a_t32 = (unsigned int*)ws;
  unsigned short* ccb = (unsigned short*)(ws + (8u << 20));
  float* sumsq = (float*)(ws + (8u << 20) + (64u << 10));
  unsigned int* xT32 = (unsigned int*)(ws + (16u << 20));

  (void)hipMemsetAsync(sumsq, 0, NB * 4, stream);
  k0_cvt<<<dim3((KK * CDIM) / 256), 256, 0, stream>>>(cc, ccb);
  k1_assign<<<dim3(8, NB), 256, 0, stream>>>(x, ccb, a_t32, xT32);
  k2_agg<<<dim3(8, NB), 256, 0, stream>>>(a_t, xT32, cc, out, sumsq);
  k3_norm<<<dim3(2048), 256, 0, stream>>>(out, sumsq);
}